// Round 18
// baseline (526.586 us; speedup 1.0000x reference)
//
#include <hip/hip_runtime.h>
#include <hip/hip_bf16.h>

typedef __attribute__((ext_vector_type(4))) float f32x4;
typedef __attribute__((ext_vector_type(2))) long long ll2;
typedef const __attribute__((address_space(1))) void* gas_t;
typedef __attribute__((address_space(3))) void* las_t;

__device__ __forceinline__ unsigned int pk4f8(float a, float b, float c,
                                              float d) {
  unsigned int r = 0;
  r = (unsigned int)__builtin_amdgcn_cvt_pk_fp8_f32(a, b, (int)r, false);
  r = (unsigned int)__builtin_amdgcn_cvt_pk_fp8_f32(c, d, (int)r, true);
  return r;
}
__device__ __forceinline__ unsigned char f8(float x) {
  return (unsigned char)(__builtin_amdgcn_cvt_pk_fp8_f32(x, 0.f, 0, false) &
                         0xff);
}
__device__ __forceinline__ long long mk64(unsigned int lo, unsigned int hi) {
  return (long long)((unsigned long long)lo |
                     ((unsigned long long)hi << 32));
}

// Transpose Wk (256x256 f32) -> WkT so make_w's reads are coalesced.
__global__ __launch_bounds__(256) void tr_wk(const float* __restrict__ Wk,
                                             float* __restrict__ WkT) {
  __shared__ float sT[64][65];
  const int b = blockIdx.x;
  const int bi = b >> 2, bj = b & 3;
  const int tid = threadIdx.x;
  const int r4 = tid >> 6, c64 = tid & 63;
#pragma unroll
  for (int p = 0; p < 16; p++)
    sT[c64][p * 4 + r4] = Wk[(bi * 64 + p * 4 + r4) * 256 + bj * 64 + c64];
  __syncthreads();
#pragma unroll
  for (int p = 0; p < 16; p++)
    WkT[(bj * 64 + p * 4 + r4) * 256 + bi * 64 + c64] = sT[p * 4 + r4][c64];
}

// WA = (Wq@Wk^T)/16, WB = Wv@Wo, wb2 = (Wq@bk)/16, cq = (bq@Wk^T)/16,
// cv = bv@Wo, cb = (bk.bq)/16
__global__ __launch_bounds__(256) void make_w(
    const float* __restrict__ WkT, const float* __restrict__ Wq,
    const float* __restrict__ Wv, const float* __restrict__ Wo,
    const float* __restrict__ bq, const float* __restrict__ bk,
    const float* __restrict__ bv, float* __restrict__ WA,
    float* __restrict__ WB, float* __restrict__ wb2,
    float* __restrict__ cq, float* __restrict__ cv, float* __restrict__ cb) {
  __shared__ float wq[256], wv[256], bqs[256], bvs[256];
  const int i = blockIdx.x, t = threadIdx.x;
  wq[t] = Wq[i * 256 + t];
  wv[t] = Wv[i * 256 + t];
  bqs[t] = bq[t];
  bvs[t] = bv[t];
  __syncthreads();
  float sa = 0.f, sb = 0.f;
#pragma unroll 8
  for (int d = 0; d < 256; d++) {
    sa = fmaf(wq[d], WkT[d * 256 + t], sa);
    sb = fmaf(wv[d], Wo[d * 256 + t], sb);
  }
  WA[i * 256 + t] = sa * 0.0625f;
  WB[i * 256 + t] = sb;
  if (t == 0) {
    float s = 0.f;
#pragma unroll 8
    for (int d = 0; d < 256; d++) s = fmaf(wq[d], bk[d], s);
    wb2[i] = s * 0.0625f;
  }
  if (i == 0) {
    float s1 = 0.f, s2 = 0.f;
#pragma unroll 8
    for (int d = 0; d < 256; d++) {
      s1 = fmaf(bqs[d], WkT[d * 256 + t], s1);
      s2 = fmaf(bvs[d], Wo[d * 256 + t], s2);
    }
    cq[t] = s1 * 0.0625f;
    cv[t] = s2;
    if (t == 0) {
      float s = 0.f;
      for (int d = 0; d < 256; d++) s = fmaf(bk[d], bqs[d], s);
      cb[0] = s * 0.0625f;
    }
  }
}

// fp8 A-panels, chunk-major, PAIRED-tile fragment-contiguous:
//   chunk (8KB) layout: [pair:8][lhi:4][l16:16][side:2][j:8] bytes — lane
//   reads 16B at pair*1024 + lane*16 covering tiles 2p (bytes 0-7) and
//   2p+1 (bytes 8-15).
// W2c (x256 scale): element (n,d): kc=d>>5, pair=n>>5, side=(n>>4)&1,
//   lhi=(d>>3)&3, l16=n&15, j=d&7
// V2c: element (c,n): kc=n>>5, pair=c>>5, side=(c>>4)&1, lhi=(n>>3)&3,
//   l16=c&15, j=n&7
// bn[b][n] = hs[n]@wb2 + cb  (f32, added pre-exp)
__global__ __launch_bounds__(256) void prep2(
    const float* __restrict__ hs, const float* __restrict__ WA,
    const float* __restrict__ WB, const float* __restrict__ cq,
    const float* __restrict__ cv, const float* __restrict__ wb2,
    const float* __restrict__ cb, unsigned char* __restrict__ W2c,
    unsigned char* __restrict__ V2c, float* __restrict__ bn) {
  __shared__ float rows[8][256];
  __shared__ float w2s[256];
  const int tid = threadIdx.x;
  const int g0 = blockIdx.x * 8;
#pragma unroll
  for (int j = 0; j < 8; j++) rows[j][tid] = hs[(size_t)(g0 + j) * 256 + tid];
  w2s[tid] = wb2[tid];
  __syncthreads();
  const float cqv = cq[tid], cvv = cv[tid];
  float aq[8], av[8];
#pragma unroll
  for (int j = 0; j < 8; j++) { aq[j] = cqv; av[j] = cvv; }
#pragma unroll 8
  for (int i = 0; i < 256; i++) {
    const float wa = WA[i * 256 + tid];
    const float wb = WB[i * 256 + tid];
#pragma unroll
    for (int j = 0; j < 8; j++) {
      aq[j] = fmaf(rows[j][i], wa, aq[j]);
      av[j] = fmaf(rows[j][i], wb, av[j]);
    }
  }
  const int bb = g0 >> 8, n0 = g0 & 255;
  // W2c: thread holds (n = n0..n0+7, d = tid); scale x256 (exp undoes)
  {
    unsigned char* dst = W2c + bb * 65536 + (tid >> 5) * 8192 +
                         (n0 >> 5) * 1024 + ((tid >> 3) & 3) * 256 +
                         ((n0 >> 4) & 1) * 8 + (tid & 7);
#pragma unroll
    for (int jj = 0; jj < 8; jj++)
      dst[((n0 & 15) + jj) * 16] = f8(aq[jj] * 256.f);
  }
  // V2c: thread holds (c = tid, n = n0..n0+7): 8 contiguous bytes
  {
    unsigned char* dst = V2c + bb * 65536 + (n0 >> 5) * 8192 +
                         (tid >> 5) * 1024 + ((n0 >> 3) & 3) * 256 +
                         (tid & 15) * 16 + ((tid >> 4) & 1) * 8;
    const unsigned int lo = pk4f8(av[0], av[1], av[2], av[3]);
    const unsigned int hi = pk4f8(av[4], av[5], av[6], av[7]);
    *(unsigned long long*)dst =
        (unsigned long long)lo | ((unsigned long long)hi << 32);
  }
  if (tid < 8) {
    float s = 0.f;
    for (int i = 0; i < 256; i++) s = fmaf(rows[tid][i], w2s[i], s);
    bn[bb * 256 + n0 + tid] = s + cb[0];
  }
}

// Stage one wave-quarter (2KB) of an 8KB fp8 chunk into LDS (identity copy).
__device__ __forceinline__ void stage_b(const unsigned char* src,
                                        unsigned char* lds, int lane) {
#pragma unroll
  for (int i = 0; i < 2; i++)
    __builtin_amdgcn_global_load_lds((gas_t)(src + i * 1024 + lane * 16),
                                     (las_t)(lds + i * 1024), 16, 0, 0);
}

// Swapped-operand fused kernel, fp8 operands: ring-4 chunk pipeline,
// stage-3-ahead, counted vmcnt; 4 blocks/CU (33KB LDS, ~111 VGPR).
// scores^T = mfma_fp8(W2*256, S^T)/256; P in regs; o^T = mfma_fp8(V2^T, P^T).
__global__ __launch_bounds__(256, 4) void pair_attn15(
    const float* __restrict__ S, const float* __restrict__ bo,
    const float* __restrict__ gamma, const float* __restrict__ beta,
    const float* __restrict__ bn, const unsigned char* __restrict__ W2c,
    const unsigned char* __restrict__ V2c, float* __restrict__ out) {
  __shared__ unsigned char sB[4][8192];  // 4 x 8KB fp8 chunk ring
  __shared__ float sBn[256];             // bn values (1KB)

  const int tid = threadIdx.x;
  const int w = tid >> 6;
  const int lane = tid & 63;
  const int l16 = lane & 15;
  const int lhi = lane >> 4;
  // bijective XCD swizzle: 8192 wgs, 8 XCDs -> each XCD owns one batch
  const int bid = blockIdx.x;
  const int idx = (bid & 7) * 1024 + (bid >> 3);
  const int rblk = idx & 3;
  const int lrow = (idx >> 2) & 255;
  const int bat = idx >> 10;

  const size_t base = ((size_t)((bat * 256 + lrow) * 256 + rblk * 64)) * 256;
  const float* Srow = S + base + (size_t)(w * 16 + l16) * 256;  // lane's row

  // ---- S B-frags straight from global (row r, d = kc*32 + lhi*8 + j), fp8
  long long sf[8];
#pragma unroll
  for (int kc = 0; kc < 8; kc++) {
    const float4 u = *(const float4*)(Srow + kc * 32 + lhi * 8);
    const float4 v = *(const float4*)(Srow + kc * 32 + lhi * 8 + 4);
    sf[kc] = mk64(pk4f8(u.x, u.y, u.z, u.w), pk4f8(v.x, v.y, v.z, v.w));
  }

  // ---- bn -> LDS (broadcast table for the exp phase)
  sBn[tid] = bn[bat * 256 + tid];

  asm volatile("s_waitcnt lgkmcnt(0)" ::: "memory");
  asm volatile("s_waitcnt vmcnt(0)" ::: "memory");
  __builtin_amdgcn_sched_barrier(0);

  const unsigned char* W2b = W2c + (size_t)bat * 65536;
  const unsigned char* V2b = V2c + (size_t)bat * 65536;

  // prologue: stage chunks 0,1,2 (ring depth 4, 3 chunks in flight)
  stage_b(W2b + 0 * 8192 + w * 2048, &sB[0][w * 2048], lane);
  stage_b(W2b + 1 * 8192 + w * 2048, &sB[1][w * 2048], lane);
  stage_b(W2b + 2 * 8192 + w * 2048, &sB[2][w * 2048], lane);

  f32x4 acc[16];
  unsigned int pkd[16];
  float psum = 0.f;
#pragma unroll
  for (int t = 0; t < 16; t++) acc[t] = (f32x4){0.f, 0.f, 0.f, 0.f};

  // bpermute byte-addrs: src lane = lhi_s*16 + l16, lhi_s base = (lhi&1)*2
  const int A0 = (((lhi & 1) * 2) * 16 + l16) * 4;
  const int A1 = A0 + 64;
  const bool hsel = (lhi >> 1) != 0;

  // ---- unified 16-chunk pipeline: t=0..7 GEMM-A (over d), 8..15 GEMM-B
#pragma unroll
  for (int t = 0; t < 16; t++) {
    if (t < 14) {
      asm volatile("s_waitcnt vmcnt(4)" ::: "memory");
    } else if (t == 14) {
      asm volatile("s_waitcnt vmcnt(2)" ::: "memory");
    } else {
      asm volatile("s_waitcnt vmcnt(0)" ::: "memory");
    }
    __builtin_amdgcn_s_barrier();
    if (t + 3 < 16) {  // stage chunk t+3 into ring slot (t+3)&3
      const int t3 = t + 3;
      const unsigned char* src =
          (t3 < 8) ? (W2b + t3 * 8192) : (V2b + (t3 - 8) * 8192);
      stage_b(src + w * 2048, &sB[t3 & 3][w * 2048], lane);
    }
    __builtin_amdgcn_sched_barrier(0);
    const unsigned char* bbuf = &sB[t & 3][0];

    if (t < 8) {
      // GEMM-A: acc[nt] += mfma(W2 pair-tiles, S^T chunk t)
      __builtin_amdgcn_s_setprio(1);
#pragma unroll
      for (int p = 0; p < 8; p++) {
        const ll2 ap = *(const ll2*)(bbuf + p * 1024 + lane * 16);
        acc[2 * p] = __builtin_amdgcn_mfma_f32_16x16x32_fp8_fp8(
            ap[0], sf[t], acc[2 * p], 0, 0, 0);
        acc[2 * p + 1] = __builtin_amdgcn_mfma_f32_16x16x32_fp8_fp8(
            ap[1], sf[t], acc[2 * p + 1], 0, 0, 0);
      }
      __builtin_amdgcn_s_setprio(0);
      if (t == 7) {
        // softmax: p = exp(s/256 + bn); denom lane-local + 2 shuffles;
        // numerators packed to fp8 (4 per u32, rg-order)
#pragma unroll
        for (int nt = 0; nt < 16; nt++) {
          const f32x4 b4 = *(const f32x4*)(sBn + nt * 16 + lhi * 4);
          const float p0 = __expf(fmaf(acc[nt][0], 0.00390625f, b4[0]));
          const float p1 = __expf(fmaf(acc[nt][1], 0.00390625f, b4[1]));
          const float p2 = __expf(fmaf(acc[nt][2], 0.00390625f, b4[2]));
          const float p3 = __expf(fmaf(acc[nt][3], 0.00390625f, b4[3]));
          psum += (p0 + p1) + (p2 + p3);
          pkd[nt] = pk4f8(p0, p1, p2, p3);
          acc[nt] = (f32x4){0.f, 0.f, 0.f, 0.f};
        }
        psum += __shfl_xor(psum, 16);
        psum += __shfl_xor(psum, 32);
      }
    } else {
      const int qq = t - 8;
      // P^T B-frag: k = n = qq*32 + lhi*8 + j; two source quads via
      // 4 bpermutes + select on (lhi>>1) for the nt parity.
      const unsigned int e0 = __builtin_amdgcn_ds_bpermute(A0, pkd[2 * qq]);
      const unsigned int e1 = __builtin_amdgcn_ds_bpermute(A1, pkd[2 * qq]);
      const unsigned int f0 =
          __builtin_amdgcn_ds_bpermute(A0, pkd[2 * qq + 1]);
      const unsigned int f1 =
          __builtin_amdgcn_ds_bpermute(A1, pkd[2 * qq + 1]);
      const long long bp = mk64(hsel ? f0 : e0, hsel ? f1 : e1);
      __builtin_amdgcn_s_setprio(1);
#pragma unroll
      for (int p = 0; p < 8; p++) {
        const ll2 ap = *(const ll2*)(bbuf + p * 1024 + lane * 16);
        acc[2 * p] = __builtin_amdgcn_mfma_f32_16x16x32_fp8_fp8(
            ap[0], bp, acc[2 * p], 0, 0, 0);
        acc[2 * p + 1] = __builtin_amdgcn_mfma_f32_16x16x32_fp8_fp8(
            ap[1], bp, acc[2 * p + 1], 0, 0, 0);
      }
      __builtin_amdgcn_s_setprio(0);
    }
  }
  __builtin_amdgcn_sched_barrier(0);

  // ---- epilogue (all lane-local): o/psum + bo + resid, LN, float4 store
  const float inv = 1.f / psum;
  float s1 = 0.f, s2 = 0.f;
#pragma unroll
  for (int ct = 0; ct < 16; ct++) {
    const float4 rz = *(const float4*)(Srow + ct * 16 + lhi * 4);
    const float4 b4 = *(const float4*)(bo + ct * 16 + lhi * 4);
    f32x4 v;
    v[0] = acc[ct][0] * inv + b4.x + rz.x;
    v[1] = acc[ct][1] * inv + b4.y + rz.y;
    v[2] = acc[ct][2] * inv + b4.z + rz.z;
    v[3] = acc[ct][3] * inv + b4.w + rz.w;
#pragma unroll
    for (int g = 0; g < 4; g++) {
      s1 += v[g];
      s2 = fmaf(v[g], v[g], s2);
    }
    acc[ct] = v;
  }
  s1 += __shfl_xor(s1, 16); s2 += __shfl_xor(s2, 16);
  s1 += __shfl_xor(s1, 32); s2 += __shfl_xor(s2, 32);
  const float mean = s1 * (1.f / 256.f);
  const float rstd = rsqrtf(s2 * (1.f / 256.f) - mean * mean + 1e-5f);
  float* Orow = out + base + (size_t)(w * 16 + l16) * 256;
#pragma unroll
  for (int ct = 0; ct < 16; ct++) {
    const float4 g4 = *(const float4*)(gamma + ct * 16 + lhi * 4);
    const float4 be4 = *(const float4*)(beta + ct * 16 + lhi * 4);
    float4 ov;
    ov.x = (acc[ct][0] - mean) * rstd * g4.x + be4.x;
    ov.y = (acc[ct][1] - mean) * rstd * g4.y + be4.y;
    ov.z = (acc[ct][2] - mean) * rstd * g4.z + be4.z;
    ov.w = (acc[ct][3] - mean) * rstd * g4.w + be4.w;
    *(float4*)(Orow + ct * 16 + lhi * 4) = ov;
  }
}

extern "C" void kernel_launch(void* const* d_in, const int* in_sizes, int n_in,
                              void* d_out, int out_size, void* d_ws, size_t ws_size,
                              hipStream_t stream) {
  const float* hs    = (const float*)d_in[0];
  const float* S     = (const float*)d_in[1];
  const float* Wq    = (const float*)d_in[2];
  const float* bq    = (const float*)d_in[3];
  const float* Wk    = (const float*)d_in[4];
  const float* bk    = (const float*)d_in[5];
  const float* Wv    = (const float*)d_in[6];
  const float* bv    = (const float*)d_in[7];
  const float* Wo    = (const float*)d_in[8];
  const float* bo    = (const float*)d_in[9];
  const float* gamma = (const float*)d_in[10];
  const float* beta  = (const float*)d_in[11];

  unsigned char* W2c = (unsigned char*)d_ws;            // 8*64KB fp8 = 512KB
  unsigned char* V2c = W2c + 8 * 65536;                 // 512KB
  float* WA  = (float*)(V2c + 8 * 65536);               // 256KB
  float* WB  = WA + 256 * 256;                          // 256KB
  float* WkT = WB + 256 * 256;                          // 256KB
  float* wb2 = WkT + 256 * 256;                         // 1KB
  float* cq  = wb2 + 256;
  float* cv  = cq + 256;
  float* cb  = cv + 256;
  float* bnp = cb + 256;                                // 8*256 f32

  tr_wk<<<16, 256, 0, stream>>>(Wk, WkT);
  make_w<<<256, 256, 0, stream>>>(WkT, Wq, Wv, Wo, bq, bk, bv, WA, WB, wb2,
                                  cq, cv, cb);
  prep2<<<256, 256, 0, stream>>>(hs, WA, WB, cq, cv, wb2, cb, W2c, V2c, bnp);
  pair_attn15<<<8192, 256, 0, stream>>>(S, bo, gamma, beta, bnp, W2c, V2c,
                                        (float*)d_out);
}

// Round 19
// 501.530 us; speedup vs baseline: 1.0500x; 1.0500x over previous
//
#include <hip/hip_runtime.h>
#include <hip/hip_bf16.h>

typedef __attribute__((ext_vector_type(8))) short short8v;
typedef __attribute__((ext_vector_type(4))) float f32x4;
typedef __attribute__((ext_vector_type(8))) unsigned short us8;
typedef const __attribute__((address_space(1))) void* gas_t;
typedef __attribute__((address_space(3))) void* las_t;

#define LDA 264  // 256 + 8 bf16 pad for the S/P tile

__device__ __forceinline__ unsigned short f2bf(float f) {
  union { __hip_bfloat16 h; unsigned short u; } c;
  c.h = __float2bfloat16(f);
  return c.u;
}
__device__ __forceinline__ unsigned int f2bf2(float lo, float hi) {
  union { __hip_bfloat162 h; unsigned int u; } c;
  c.h = __float22bfloat162_rn(make_float2(lo, hi));
  return c.u;
}

// Transpose Wk (256x256 f32) -> WkT so make_w's reads are coalesced.
__global__ __launch_bounds__(256) void tr_wk(const float* __restrict__ Wk,
                                             float* __restrict__ WkT) {
  __shared__ float sT[64][65];
  const int b = blockIdx.x;
  const int bi = b >> 2, bj = b & 3;
  const int tid = threadIdx.x;
  const int r4 = tid >> 6, c64 = tid & 63;
#pragma unroll
  for (int p = 0; p < 16; p++)
    sT[c64][p * 4 + r4] = Wk[(bi * 64 + p * 4 + r4) * 256 + bj * 64 + c64];
  __syncthreads();
#pragma unroll
  for (int p = 0; p < 16; p++)
    WkT[(bj * 64 + p * 4 + r4) * 256 + bi * 64 + c64] = sT[p * 4 + r4][c64];
}

// WA = (Wq@Wk^T)/16, WB = Wv@Wo, wb2 = (Wq@bk)/16, cq = (bq@Wk^T)/16,
// cv = bv@Wo, cb = (bk.bq)/16   (Wk accessed via WkT -> coalesced)
__global__ __launch_bounds__(256) void make_w(
    const float* __restrict__ WkT, const float* __restrict__ Wq,
    const float* __restrict__ Wv, const float* __restrict__ Wo,
    const float* __restrict__ bq, const float* __restrict__ bk,
    const float* __restrict__ bv, float* __restrict__ WA,
    float* __restrict__ WB, float* __restrict__ wb2,
    float* __restrict__ cq, float* __restrict__ cv, float* __restrict__ cb) {
  __shared__ float wq[256], wv[256], bqs[256], bvs[256];
  const int i = blockIdx.x, t = threadIdx.x;
  wq[t] = Wq[i * 256 + t];
  wv[t] = Wv[i * 256 + t];
  bqs[t] = bq[t];
  bvs[t] = bv[t];
  __syncthreads();
  float sa = 0.f, sb = 0.f;
#pragma unroll 8
  for (int d = 0; d < 256; d++) {
    sa = fmaf(wq[d], WkT[d * 256 + t], sa);
    sb = fmaf(wv[d], Wo[d * 256 + t], sb);
  }
  WA[i * 256 + t] = sa * 0.0625f;
  WB[i * 256 + t] = sb;
  if (t == 0) {
    float s = 0.f;
#pragma unroll 8
    for (int d = 0; d < 256; d++) s = fmaf(wq[d], bk[d], s);
    wb2[i] = s * 0.0625f;
  }
  if (i == 0) {
    float s1 = 0.f, s2 = 0.f;
#pragma unroll 8
    for (int d = 0; d < 256; d++) {
      s1 = fmaf(bqs[d], WkT[d * 256 + t], s1);
      s2 = fmaf(bvs[d], Wo[d * 256 + t], s2);
    }
    cq[t] = s1 * 0.0625f;
    cv[t] = s2;
    if (t == 0) {
      float s = 0.f;
      for (int d = 0; d < 256; d++) s = fmaf(bk[d], bqs[d], s);
      cb[0] = s * 0.0625f;
    }
  }
}

// Chunk-major, MFMA-fragment-contiguous B layouts. Wave chunk (4KB) layout:
//   [nt:4][lhi:4][l16:16][j:8]  ->  lane (lhi*16+l16) reads frag nt at
//   byte  nt*1024 + lane*16  (perfectly coalesced, conflict-free ds_read).
// W2c: element (n, k):  idx = b*65536 + (k>>5)*8192 + (n>>6)*2048
//                           + ((n>>4)&3)*512 + ((k>>3)&3)*128 + (n&15)*8 + (k&7)
// V2c: element (c, n):  idx = b*65536 + (n>>5)*8192 + (c>>6)*2048
//                           + ((c>>4)&3)*512 + ((n>>3)&3)*128 + (c&15)*8 + (n&7)
// bn[b][n] = hs[n]@wb2 + cb
__global__ __launch_bounds__(256) void prep2(
    const float* __restrict__ hs, const float* __restrict__ WA,
    const float* __restrict__ WB, const float* __restrict__ wb2,
    const float* __restrict__ cq, const float* __restrict__ cv,
    const float* __restrict__ cb, unsigned short* __restrict__ W2c,
    unsigned short* __restrict__ V2c, float* __restrict__ bn) {
  __shared__ float rows[8][256];
  __shared__ float w2s[256];
  const int tid = threadIdx.x;
  const int g0 = blockIdx.x * 8;
#pragma unroll
  for (int j = 0; j < 8; j++) rows[j][tid] = hs[(size_t)(g0 + j) * 256 + tid];
  w2s[tid] = wb2[tid];
  __syncthreads();
  const float cqv = cq[tid], cvv = cv[tid];
  float aq[8], av[8];
#pragma unroll
  for (int j = 0; j < 8; j++) { aq[j] = cqv; av[j] = cvv; }
#pragma unroll 8
  for (int i = 0; i < 256; i++) {
    const float wa = WA[i * 256 + tid];
    const float wb = WB[i * 256 + tid];
#pragma unroll
    for (int j = 0; j < 8; j++) {
      aq[j] = fmaf(rows[j][i], wa, aq[j]);
      av[j] = fmaf(rows[j][i], wb, av[j]);
    }
  }
  const int bb = g0 >> 8, n0 = g0 & 255;
  // W2c: thread holds k=tid for n=n0..n0+7
  {
    const int kc = tid >> 5, lhi = (tid >> 3) & 3, j = tid & 7;
    const int w = n0 >> 6, nt = (n0 >> 4) & 3, l0 = n0 & 15;
    unsigned short* dst = W2c + bb * 65536 + kc * 8192 + w * 2048 + nt * 512 +
                          lhi * 128 + l0 * 8 + j;
#pragma unroll
    for (int jj = 0; jj < 8; jj++) dst[jj * 8] = f2bf(aq[jj]);
  }
  // V2c: thread holds c=tid for n=n0..n0+7 (contiguous j -> us8)
  {
    const int kc = n0 >> 5, lhi = (n0 >> 3) & 3;
    const int w = tid >> 6, nt = (tid >> 4) & 3, l16 = tid & 15;
    us8 vp;
#pragma unroll
    for (int j = 0; j < 8; j++) vp[j] = f2bf(av[j]);
    *(us8*)(V2c + bb * 65536 + kc * 8192 + w * 2048 + nt * 512 + lhi * 128 +
            l16 * 8) = vp;
  }
  if (tid < 8) {
    float s = 0.f;
    for (int i = 0; i < 256; i++) s = fmaf(rows[tid][i], w2s[i], s);
    bn[bb * 256 + n0 + tid] = s + cb[0];
  }
}

// Stage one wave-private 4KB B-chunk into LDS (identity copy; layout already
// fragment-contiguous). LDS dest wave-uniform base; HW adds lane*16.
__device__ __forceinline__ void stage_b(const unsigned short* src_wave,
                                        unsigned short* lds_wave, int lane) {
#pragma unroll
  for (int i = 0; i < 4; i++) {
    const unsigned short* g = src_wave + i * 512 + lane * 8;
    unsigned short* l = lds_wave + i * 512;
    __builtin_amdgcn_global_load_lds((gas_t)g, (las_t)l, 16, 0, 0);
  }
}

// One block: 64 r-rows of one (b,l) pair. B double-buffered in LDS via
// global_load_lds + counted vmcnt; stage issued BEFORE the MFMAs (2-chunk
// in-flight window). Raw s_barrier around exp keeps V-loads in flight.
__global__ __launch_bounds__(256, 2) void pair_attn10(
    const float* __restrict__ S, const float* __restrict__ bo,
    const float* __restrict__ gamma, const float* __restrict__ beta,
    const float* __restrict__ bn, const unsigned short* __restrict__ W2c,
    const unsigned short* __restrict__ V2c, float* __restrict__ out) {
  __shared__ unsigned short sA[64 * LDA];  // S (bf16), then P (bf16)
  __shared__ unsigned short sB[2][8192];   // 2 x 16KB B-chunk double buffer
  __shared__ float sRed[64 * 8];           // LN partial sums

  const int tid = threadIdx.x;
  const int w = tid >> 6;
  const int lane = tid & 63;
  const int l16 = lane & 15;
  const int lhi = lane >> 4;
  // bijective XCD swizzle: 8192 wgs, 8 XCDs -> each XCD owns one batch
  const int bid = blockIdx.x;
  const int idx = (bid & 7) * 1024 + (bid >> 3);
  const int rblk = idx & 3;
  const int lrow = (idx >> 2) & 255;
  const int bat = idx >> 10;

  const size_t base = ((size_t)((bat * 256 + lrow) * 256 + rblk * 64)) * 256;
  const float* Sblk = S + base;

  // ---- stage S rows -> sA (bf16), 16B LDS writes
#pragma unroll
  for (int it = 0; it < 8; it++) {
    const int c = tid + it * 256;
    const int row = c >> 5, col = (c & 31) << 3;
    const float4 u = *(const float4*)(Sblk + row * 256 + col);
    const float4 v = *(const float4*)(Sblk + row * 256 + col + 4);
    us8 p;
    unsigned int* pu = (unsigned int*)&p;
    pu[0] = f2bf2(u.x, u.y);
    pu[1] = f2bf2(u.z, u.w);
    pu[2] = f2bf2(v.x, v.y);
    pu[3] = f2bf2(v.z, v.w);
    *(us8*)(sA + row * LDA + col) = p;
  }
  // softmax bias (the ONLY global load before the fenced region)
  float bnv[4];
#pragma unroll
  for (int nt = 0; nt < 4; nt++)
    bnv[nt] = bn[bat * 256 + w * 64 + nt * 16 + l16];
  __syncthreads();  // B1 (drains all vmem)

  const unsigned short* W2b = W2c + (size_t)bat * 65536;
  const unsigned short* V2b = V2c + (size_t)bat * 65536;

  // ===== fenced VMEM region: only our global_load_lds in flight =====
  asm volatile("s_waitcnt vmcnt(0)" ::: "memory");
  __builtin_amdgcn_sched_barrier(0);

  // prologue: chunks 0,1 of W
  stage_b(W2b + 0 * 8192 + w * 2048, &sB[0][w * 2048], lane);
  stage_b(W2b + 1 * 8192 + w * 2048, &sB[1][w * 2048], lane);

  f32x4 acc[4][4];
#pragma unroll
  for (int rt = 0; rt < 4; rt++)
#pragma unroll
    for (int nt = 0; nt < 4; nt++) acc[rt][nt] = (f32x4){0.f, 0.f, 0.f, 0.f};

  // ---- GEMM-A: scores = S @ W2 (8 chunks, dbuf; stage before MFMAs)
#pragma unroll
  for (int q = 0; q < 8; q++) {
    asm volatile("s_waitcnt vmcnt(4)" ::: "memory");  // chunk q arrived
    __builtin_amdgcn_sched_barrier(0);
    const unsigned short* bb = &sB[q & 1][w * 2048];
    short8v a[4], bf[4];
#pragma unroll
    for (int rt = 0; rt < 4; rt++)
      a[rt] = *(const short8v*)(sA + (rt * 16 + l16) * LDA + q * 32 + lhi * 8);
#pragma unroll
    for (int nt = 0; nt < 4; nt++)
      bf[nt] = *(const short8v*)(bb + nt * 512 + lane * 8);
    asm volatile("s_waitcnt lgkmcnt(0)" ::: "memory");  // frags in regs
    __builtin_amdgcn_sched_barrier(0);
    if (q < 6)
      stage_b(W2b + (q + 2) * 8192 + w * 2048, &sB[q & 1][w * 2048], lane);
    else  // V chunks 0,1 issued under the exp phase
      stage_b(V2b + (q - 6) * 8192 + w * 2048, &sB[q & 1][w * 2048], lane);
    __builtin_amdgcn_sched_barrier(0);
#pragma unroll
    for (int rt = 0; rt < 4; rt++)
#pragma unroll
      for (int nt = 0; nt < 4; nt++)
        acc[rt][nt] = __builtin_amdgcn_mfma_f32_16x16x32_bf16(
            a[rt], bf[nt], acc[rt][nt], 0, 0, 0);
  }

  // ---- exp phase between raw barriers (NO vmcnt drain: V0/V1 in flight)
  asm volatile("s_waitcnt lgkmcnt(0)" ::: "memory");
  __builtin_amdgcn_s_barrier();  // all waves done reading sA (S)
#pragma unroll
  for (int rt = 0; rt < 4; rt++)
#pragma unroll
    for (int nt = 0; nt < 4; nt++)
#pragma unroll
      for (int rg = 0; rg < 4; rg++)
        sA[(rt * 16 + lhi * 4 + rg) * LDA + (w * 64 + nt * 16 + l16)] =
            f2bf(__expf(acc[rt][nt][rg] + bnv[nt]));
  asm volatile("s_waitcnt lgkmcnt(0)" ::: "memory");
  __builtin_amdgcn_s_barrier();  // P visible to all waves

  // ---- GEMM-B: o = P_un @ V2, plus P row-sums via ones-MFMA
  short8v onesv;
#pragma unroll
  for (int j = 0; j < 8; j++) onesv[j] = (short)0x3F80;  // bf16 1.0
  f32x4 ps[4];
#pragma unroll
  for (int rt = 0; rt < 4; rt++) {
    ps[rt] = (f32x4){0.f, 0.f, 0.f, 0.f};
#pragma unroll
    for (int nt = 0; nt < 4; nt++) acc[rt][nt] = (f32x4){0.f, 0.f, 0.f, 0.f};
  }
#pragma unroll
  for (int q = 0; q < 8; q++) {
    if (q < 7) {
      asm volatile("s_waitcnt vmcnt(4)" ::: "memory");
    } else {
      asm volatile("s_waitcnt vmcnt(0)" ::: "memory");
    }
    __builtin_amdgcn_sched_barrier(0);
    const unsigned short* bb = &sB[q & 1][w * 2048];
    short8v a[4], bf[4];
#pragma unroll
    for (int rt = 0; rt < 4; rt++)
      a[rt] = *(const short8v*)(sA + (rt * 16 + l16) * LDA + q * 32 + lhi * 8);
#pragma unroll
    for (int nt = 0; nt < 4; nt++)
      bf[nt] = *(const short8v*)(bb + nt * 512 + lane * 8);
    asm volatile("s_waitcnt lgkmcnt(0)" ::: "memory");
    __builtin_amdgcn_sched_barrier(0);
    if (q < 6)
      stage_b(V2b + (q + 2) * 8192 + w * 2048, &sB[q & 1][w * 2048], lane);
    __builtin_amdgcn_sched_barrier(0);
#pragma unroll
    for (int rt = 0; rt < 4; rt++) {
#pragma unroll
      for (int nt = 0; nt < 4; nt++)
        acc[rt][nt] = __builtin_amdgcn_mfma_f32_16x16x32_bf16(
            a[rt], bf[nt], acc[rt][nt], 0, 0, 0);
      ps[rt] = __builtin_amdgcn_mfma_f32_16x16x32_bf16(a[rt], onesv, ps[rt],
                                                       0, 0, 0);
    }
  }
  __builtin_amdgcn_sched_barrier(0);
  // ===== end fenced region =====

  // ---- epilogue: o/rowsum + bo + S residual (f32), LN partial sums
  float bov[4], gv[4], bev[4];
#pragma unroll
  for (int nt = 0; nt < 4; nt++) {
    const int col = w * 64 + nt * 16 + l16;
    bov[nt] = bo[col];
    gv[nt] = gamma[col];
    bev[nt] = beta[col];
  }
#pragma unroll
  for (int rt = 0; rt < 4; rt++)
#pragma unroll
    for (int rg = 0; rg < 4; rg++) {
      const int row = rt * 16 + lhi * 4 + rg;
      const float invr = 1.f / ps[rt][rg];
      const float* Srow = Sblk + row * 256;
      float s1 = 0.f, s2 = 0.f;
#pragma unroll
      for (int nt = 0; nt < 4; nt++) {
        const int col = w * 64 + nt * 16 + l16;
        const float val = acc[rt][nt][rg] * invr + bov[nt] + Srow[col];
        acc[rt][nt][rg] = val;
        s1 += val;
        s2 = fmaf(val, val, s2);
      }
      s1 += __shfl_xor(s1, 1); s2 += __shfl_xor(s2, 1);
      s1 += __shfl_xor(s1, 2); s2 += __shfl_xor(s2, 2);
      s1 += __shfl_xor(s1, 4); s2 += __shfl_xor(s2, 4);
      s1 += __shfl_xor(s1, 8); s2 += __shfl_xor(s2, 8);
      if (l16 == 0) { sRed[row * 8 + w] = s1; sRed[row * 8 + 4 + w] = s2; }
    }
  __syncthreads();  // B4

  float* O = out + base;
#pragma unroll
  for (int rt = 0; rt < 4; rt++)
#pragma unroll
    for (int rg = 0; rg < 4; rg++) {
      const int row = rt * 16 + lhi * 4 + rg;
      f32x4 sa = *(f32x4*)(sRed + row * 8);
      f32x4 sq = *(f32x4*)(sRed + row * 8 + 4);
      const float mean = (sa[0] + sa[1] + sa[2] + sa[3]) * (1.f / 256.f);
      const float ex2 = (sq[0] + sq[1] + sq[2] + sq[3]) * (1.f / 256.f);
      const float rstd = rsqrtf(ex2 - mean * mean + 1e-5f);
      float* Orow = O + row * 256;
#pragma unroll
      for (int nt = 0; nt < 4; nt++) {
        const int col = w * 64 + nt * 16 + l16;
        Orow[col] = (acc[rt][nt][rg] - mean) * rstd * gv[nt] + bev[nt];
      }
    }
}

extern "C" void kernel_launch(void* const* d_in, const int* in_sizes, int n_in,
                              void* d_out, int out_size, void* d_ws, size_t ws_size,
                              hipStream_t stream) {
  const float* hs    = (const float*)d_in[0];
  const float* S     = (const float*)d_in[1];
  const float* Wq    = (const float*)d_in[2];
  const float* bq    = (const float*)d_in[3];
  const float* Wk    = (const float*)d_in[4];
  const float* bk    = (const float*)d_in[5];
  const float* Wv    = (const float*)d_in[6];
  const float* bv    = (const float*)d_in[7];
  const float* Wo    = (const float*)d_in[8];
  const float* bo    = (const float*)d_in[9];
  const float* gamma = (const float*)d_in[10];
  const float* beta  = (const float*)d_in[11];

  unsigned short* W2c = (unsigned short*)d_ws;          // 8*256*256 bf16 = 1MB
  unsigned short* V2c = W2c + 8 * 256 * 256;            // 1MB
  float* WA  = (float*)(V2c + 8 * 256 * 256);           // 256KB
  float* WB  = WA + 256 * 256;                          // 256KB
  float* WkT = WB + 256 * 256;                          // 256KB
  float* wb2 = WkT + 256 * 256;                         // 1KB
  float* cq  = wb2 + 256;
  float* cv  = cq + 256;
  float* cb  = cv + 256;
  float* bnp = cb + 256;                                // 8*256 f32

  tr_wk<<<16, 256, 0, stream>>>(Wk, WkT);
  make_w<<<256, 256, 0, stream>>>(WkT, Wq, Wv, Wo, bq, bk, bv, WA, WB, wb2,
                                  cq, cv, cb);
  prep2<<<256, 256, 0, stream>>>(hs, WA, WB, wb2, cq, cv, cb, W2c, V2c, bnp);
  pair_attn10<<<8192, 256, 0, stream>>>(S, bo, gamma, beta, bnp, W2c, V2c,
                                        (float*)d_out);
}

// Round 20
// 483.906 us; speedup vs baseline: 1.0882x; 1.0364x over previous
//
#include <hip/hip_runtime.h>
#include <hip/hip_bf16.h>

typedef __attribute__((ext_vector_type(8))) short short8v;
typedef __attribute__((ext_vector_type(4))) float f32x4;
typedef __attribute__((ext_vector_type(8))) unsigned short us8;

#define LDA 264  // 256 + 8 bf16 pad for the S/P tile

__device__ __forceinline__ unsigned short f2bf(float f) {
  union { __hip_bfloat16 h; unsigned short u; } c;
  c.h = __float2bfloat16(f);
  return c.u;
}
__device__ __forceinline__ unsigned int f2bf2(float lo, float hi) {
  union { __hip_bfloat162 h; unsigned int u; } c;
  c.h = __float22bfloat162_rn(make_float2(lo, hi));
  return c.u;
}

// Transpose Wk (256x256 f32) -> WkT so make_w's reads are coalesced.
__global__ __launch_bounds__(256) void tr_wk(const float* __restrict__ Wk,
                                             float* __restrict__ WkT) {
  __shared__ float sT[64][65];
  const int b = blockIdx.x;
  const int bi = b >> 2, bj = b & 3;
  const int tid = threadIdx.x;
  const int r4 = tid >> 6, c64 = tid & 63;
#pragma unroll
  for (int p = 0; p < 16; p++)
    sT[c64][p * 4 + r4] = Wk[(bi * 64 + p * 4 + r4) * 256 + bj * 64 + c64];
  __syncthreads();
#pragma unroll
  for (int p = 0; p < 16; p++)
    WkT[(bj * 64 + p * 4 + r4) * 256 + bi * 64 + c64] = sT[p * 4 + r4][c64];
}

// WA = (Wq@Wk^T)/16, WB = Wv@Wo, wb2 = (Wq@bk)/16, cq = (bq@Wk^T)/16,
// cv = bv@Wo, cb = (bk.bq)/16   (Wk accessed via WkT -> coalesced)
__global__ __launch_bounds__(256) void make_w(
    const float* __restrict__ WkT, const float* __restrict__ Wq,
    const float* __restrict__ Wv, const float* __restrict__ Wo,
    const float* __restrict__ bq, const float* __restrict__ bk,
    const float* __restrict__ bv, float* __restrict__ WA,
    float* __restrict__ WB, float* __restrict__ wb2,
    float* __restrict__ cq, float* __restrict__ cv, float* __restrict__ cb) {
  __shared__ float wq[256], wv[256], bqs[256], bvs[256];
  const int i = blockIdx.x, t = threadIdx.x;
  wq[t] = Wq[i * 256 + t];
  wv[t] = Wv[i * 256 + t];
  bqs[t] = bq[t];
  bvs[t] = bv[t];
  __syncthreads();
  float sa = 0.f, sb = 0.f;
#pragma unroll 8
  for (int d = 0; d < 256; d++) {
    sa = fmaf(wq[d], WkT[d * 256 + t], sa);
    sb = fmaf(wv[d], Wo[d * 256 + t], sb);
  }
  WA[i * 256 + t] = sa * 0.0625f;
  WB[i * 256 + t] = sb;
  if (t == 0) {
    float s = 0.f;
#pragma unroll 8
    for (int d = 0; d < 256; d++) s = fmaf(wq[d], bk[d], s);
    wb2[i] = s * 0.0625f;
  }
  if (i == 0) {
    float s1 = 0.f, s2 = 0.f;
#pragma unroll 8
    for (int d = 0; d < 256; d++) {
      s1 = fmaf(bqs[d], WkT[d * 256 + t], s1);
      s2 = fmaf(bvs[d], Wo[d * 256 + t], s2);
    }
    cq[t] = s1 * 0.0625f;
    cv[t] = s2;
    if (t == 0) {
      float s = 0.f;
      for (int d = 0; d < 256; d++) s = fmaf(bk[d], bqs[d], s);
      cb[0] = s * 0.0625f;
    }
  }
}

// Chunk-major, MFMA-fragment-contiguous B layouts. Wave chunk (4KB) layout:
//   [nt:4][lhi:4][l16:16][j:8]  ->  lane (lhi*16+l16) reads frag nt at
//   byte  nt*1024 + lane*16  (coalesced 1KB global load per fragment).
// W2c: element (n, k):  idx = b*65536 + (k>>5)*8192 + (n>>6)*2048
//                           + ((n>>4)&3)*512 + ((k>>3)&3)*128 + (n&15)*8 + (k&7)
// V2c: element (c, n):  idx = b*65536 + (n>>5)*8192 + (c>>6)*2048
//                           + ((c>>4)&3)*512 + ((n>>3)&3)*128 + (c&15)*8 + (n&7)
// bn[b][n] = hs[n]@wb2 + cb
__global__ __launch_bounds__(256) void prep2(
    const float* __restrict__ hs, const float* __restrict__ WA,
    const float* __restrict__ WB, const float* __restrict__ wb2,
    const float* __restrict__ cq, const float* __restrict__ cv,
    const float* __restrict__ cb, unsigned short* __restrict__ W2c,
    unsigned short* __restrict__ V2c, float* __restrict__ bn) {
  __shared__ float rows[8][256];
  __shared__ float w2s[256];
  const int tid = threadIdx.x;
  const int g0 = blockIdx.x * 8;
#pragma unroll
  for (int j = 0; j < 8; j++) rows[j][tid] = hs[(size_t)(g0 + j) * 256 + tid];
  w2s[tid] = wb2[tid];
  __syncthreads();
  const float cqv = cq[tid], cvv = cv[tid];
  float aq[8], av[8];
#pragma unroll
  for (int j = 0; j < 8; j++) { aq[j] = cqv; av[j] = cvv; }
#pragma unroll 8
  for (int i = 0; i < 256; i++) {
    const float wa = WA[i * 256 + tid];
    const float wb = WB[i * 256 + tid];
#pragma unroll
    for (int j = 0; j < 8; j++) {
      aq[j] = fmaf(rows[j][i], wa, aq[j]);
      av[j] = fmaf(rows[j][i], wb, av[j]);
    }
  }
  const int bb = g0 >> 8, n0 = g0 & 255;
  // W2c: thread holds k=tid for n=n0..n0+7
  {
    const int kc = tid >> 5, lhi = (tid >> 3) & 3, j = tid & 7;
    const int w = n0 >> 6, nt = (n0 >> 4) & 3, l0 = n0 & 15;
    unsigned short* dst = W2c + bb * 65536 + kc * 8192 + w * 2048 + nt * 512 +
                          lhi * 128 + l0 * 8 + j;
#pragma unroll
    for (int jj = 0; jj < 8; jj++) dst[jj * 8] = f2bf(aq[jj]);
  }
  // V2c: thread holds c=tid for n=n0..n0+7 (contiguous j -> us8)
  {
    const int kc = n0 >> 5, lhi = (n0 >> 3) & 3;
    const int w = tid >> 6, nt = (tid >> 4) & 3, l16 = tid & 15;
    us8 vp;
#pragma unroll
    for (int j = 0; j < 8; j++) vp[j] = f2bf(av[j]);
    *(us8*)(V2c + bb * 65536 + kc * 8192 + w * 2048 + nt * 512 + lhi * 128 +
            l16 * 8) = vp;
  }
  if (tid < 8) {
    float s = 0.f;
    for (int i = 0; i < 256; i++) s = fmaf(rows[tid][i], w2s[i], s);
    bn[bb * 256 + n0 + tid] = s + cb[0];
  }
}

// One block: 64 r-rows of one (b,l) pair. B-fragments loaded DIRECTLY from
// global into registers (fragment-contiguous layout => coalesced 1KB loads,
// L2-hot). No B LDS pipe: 36KB LDS -> 3 blocks/CU at (256,3).
__global__ __launch_bounds__(256, 3) void pair_attn16(
    const float* __restrict__ S, const float* __restrict__ bo,
    const float* __restrict__ gamma, const float* __restrict__ beta,
    const float* __restrict__ bn, const unsigned short* __restrict__ W2c,
    const unsigned short* __restrict__ V2c, float* __restrict__ out) {
  __shared__ unsigned short sA[64 * LDA];  // S (bf16), then P (bf16)
  __shared__ float sRed[64 * 8];           // LN partial sums

  const int tid = threadIdx.x;
  const int w = tid >> 6;
  const int lane = tid & 63;
  const int l16 = lane & 15;
  const int lhi = lane >> 4;
  // bijective XCD swizzle: 8192 wgs, 8 XCDs -> each XCD owns one batch
  const int bid = blockIdx.x;
  const int idx = (bid & 7) * 1024 + (bid >> 3);
  const int rblk = idx & 3;
  const int lrow = (idx >> 2) & 255;
  const int bat = idx >> 10;

  const size_t base = ((size_t)((bat * 256 + lrow) * 256 + rblk * 64)) * 256;
  const float* Sblk = S + base;

  // ---- stage S rows -> sA (bf16), 16B LDS writes
#pragma unroll
  for (int it = 0; it < 8; it++) {
    const int c = tid + it * 256;
    const int row = c >> 5, col = (c & 31) << 3;
    const float4 u = *(const float4*)(Sblk + row * 256 + col);
    const float4 v = *(const float4*)(Sblk + row * 256 + col + 4);
    us8 p;
    unsigned int* pu = (unsigned int*)&p;
    pu[0] = f2bf2(u.x, u.y);
    pu[1] = f2bf2(u.z, u.w);
    pu[2] = f2bf2(v.x, v.y);
    pu[3] = f2bf2(v.z, v.w);
    *(us8*)(sA + row * LDA + col) = p;
  }
  float bnv[4];
#pragma unroll
  for (int nt = 0; nt < 4; nt++)
    bnv[nt] = bn[bat * 256 + w * 64 + nt * 16 + l16];
  __syncthreads();  // B1: S staged

  // wave's private column-slice bases (fragment nt at + nt*512 + lane*8)
  const unsigned short* Wb = W2c + (size_t)bat * 65536 + w * 2048;
  const unsigned short* Vb = V2c + (size_t)bat * 65536 + w * 2048;

  f32x4 acc[4][4];
#pragma unroll
  for (int rt = 0; rt < 4; rt++)
#pragma unroll
    for (int nt = 0; nt < 4; nt++) acc[rt][nt] = (f32x4){0.f, 0.f, 0.f, 0.f};

  // ---- GEMM-A: scores = S @ W2; B-frags direct from global (L2-hot)
#pragma unroll
  for (int q = 0; q < 8; q++) {
    short8v a[4], bf[4];
#pragma unroll
    for (int nt = 0; nt < 4; nt++)
      bf[nt] = *(const short8v*)(Wb + q * 8192 + nt * 512 + lane * 8);
#pragma unroll
    for (int rt = 0; rt < 4; rt++)
      a[rt] = *(const short8v*)(sA + (rt * 16 + l16) * LDA + q * 32 + lhi * 8);
#pragma unroll
    for (int rt = 0; rt < 4; rt++)
#pragma unroll
      for (int nt = 0; nt < 4; nt++)
        acc[rt][nt] = __builtin_amdgcn_mfma_f32_16x16x32_bf16(
            a[rt], bf[nt], acc[rt][nt], 0, 0, 0);
  }
  __syncthreads();  // B2: all waves done reading sA (S)

  // ---- exp phase: p = exp(s + bn), unnormalized -> sA (overwrite S)
#pragma unroll
  for (int rt = 0; rt < 4; rt++)
#pragma unroll
    for (int nt = 0; nt < 4; nt++)
#pragma unroll
      for (int rg = 0; rg < 4; rg++)
        sA[(rt * 16 + lhi * 4 + rg) * LDA + (w * 64 + nt * 16 + l16)] =
            f2bf(__expf(acc[rt][nt][rg] + bnv[nt]));
  __syncthreads();  // B3: P visible to all waves

  // ---- GEMM-B: o = P_un @ V2, plus P row-sums via ones-MFMA
  short8v onesv;
#pragma unroll
  for (int j = 0; j < 8; j++) onesv[j] = (short)0x3F80;  // bf16 1.0
  f32x4 ps[4];
#pragma unroll
  for (int rt = 0; rt < 4; rt++) {
    ps[rt] = (f32x4){0.f, 0.f, 0.f, 0.f};
#pragma unroll
    for (int nt = 0; nt < 4; nt++) acc[rt][nt] = (f32x4){0.f, 0.f, 0.f, 0.f};
  }
#pragma unroll
  for (int q = 0; q < 8; q++) {
    short8v a[4], bf[4];
#pragma unroll
    for (int nt = 0; nt < 4; nt++)
      bf[nt] = *(const short8v*)(Vb + q * 8192 + nt * 512 + lane * 8);
#pragma unroll
    for (int rt = 0; rt < 4; rt++)
      a[rt] = *(const short8v*)(sA + (rt * 16 + l16) * LDA + q * 32 + lhi * 8);
#pragma unroll
    for (int rt = 0; rt < 4; rt++) {
#pragma unroll
      for (int nt = 0; nt < 4; nt++)
        acc[rt][nt] = __builtin_amdgcn_mfma_f32_16x16x32_bf16(
            a[rt], bf[nt], acc[rt][nt], 0, 0, 0);
      ps[rt] = __builtin_amdgcn_mfma_f32_16x16x32_bf16(a[rt], onesv, ps[rt],
                                                       0, 0, 0);
    }
  }

  // ---- epilogue: o/rowsum + bo + S residual (f32, L2), LN partial sums
  float bov[4], gv[4], bev[4];
#pragma unroll
  for (int nt = 0; nt < 4; nt++) {
    const int col = w * 64 + nt * 16 + l16;
    bov[nt] = bo[col];
    gv[nt] = gamma[col];
    bev[nt] = beta[col];
  }
#pragma unroll
  for (int rt = 0; rt < 4; rt++)
#pragma unroll
    for (int rg = 0; rg < 4; rg++) {
      const int row = rt * 16 + lhi * 4 + rg;
      const float invr = 1.f / ps[rt][rg];
      const float* Srow = Sblk + row * 256;
      float s1 = 0.f, s2 = 0.f;
#pragma unroll
      for (int nt = 0; nt < 4; nt++) {
        const int col = w * 64 + nt * 16 + l16;
        const float val = acc[rt][nt][rg] * invr + bov[nt] + Srow[col];
        acc[rt][nt][rg] = val;
        s1 += val;
        s2 = fmaf(val, val, s2);
      }
      s1 += __shfl_xor(s1, 1); s2 += __shfl_xor(s2, 1);
      s1 += __shfl_xor(s1, 2); s2 += __shfl_xor(s2, 2);
      s1 += __shfl_xor(s1, 4); s2 += __shfl_xor(s2, 4);
      s1 += __shfl_xor(s1, 8); s2 += __shfl_xor(s2, 8);
      if (l16 == 0) { sRed[row * 8 + w] = s1; sRed[row * 8 + 4 + w] = s2; }
    }
  __syncthreads();  // B4

  float* O = out + base;
#pragma unroll
  for (int rt = 0; rt < 4; rt++)
#pragma unroll
    for (int rg = 0; rg < 4; rg++) {
      const int row = rt * 16 + lhi * 4 + rg;
      f32x4 sa = *(f32x4*)(sRed + row * 8);
      f32x4 sq = *(f32x4*)(sRed + row * 8 + 4);
      const float mean = (sa[0] + sa[1] + sa[2] + sa[3]) * (1.f / 256.f);
      const float ex2 = (sq[0] + sq[1] + sq[2] + sq[3]) * (1.f / 256.f);
      const float rstd = rsqrtf(ex2 - mean * mean + 1e-5f);
      float* Orow = O + row * 256;
#pragma unroll
      for (int nt = 0; nt < 4; nt++) {
        const int col = w * 64 + nt * 16 + l16;
        Orow[col] = (acc[rt][nt][rg] - mean) * rstd * gv[nt] + bev[nt];
      }
    }
}

extern "C" void kernel_launch(void* const* d_in, const int* in_sizes, int n_in,
                              void* d_out, int out_size, void* d_ws, size_t ws_size,
                              hipStream_t stream) {
  const float* hs    = (const float*)d_in[0];
  const float* S     = (const float*)d_in[1];
  const float* Wq    = (const float*)d_in[2];
  const float* bq    = (const float*)d_in[3];
  const float* Wk    = (const float*)d_in[4];
  const float* bk    = (const float*)d_in[5];
  const float* Wv    = (const float*)d_in[6];
  const float* bv    = (const float*)d_in[7];
  const float* Wo    = (const float*)d_in[8];
  const float* bo    = (const float*)d_in[9];
  const float* gamma = (const float*)d_in[10];
  const float* beta  = (const float*)d_in[11];

  unsigned short* W2c = (unsigned short*)d_ws;          // 8*256*256 bf16 = 1MB
  unsigned short* V2c = W2c + 8 * 256 * 256;            // 1MB
  float* WA  = (float*)(V2c + 8 * 256 * 256);           // 256KB
  float* WB  = WA + 256 * 256;                          // 256KB
  float* WkT = WB + 256 * 256;                          // 256KB
  float* wb2 = WkT + 256 * 256;                         // 1KB
  float* cq  = wb2 + 256;
  float* cv  = cq + 256;
  float* cb  = cv + 256;
  float* bnp = cb + 256;                                // 8*256 f32

  tr_wk<<<16, 256, 0, stream>>>(Wk, WkT);
  make_w<<<256, 256, 0, stream>>>(WkT, Wq, Wv, Wo, bq, bk, bv, WA, WB, wb2,
                                  cq, cv, cb);
  prep2<<<256, 256, 0, stream>>>(hs, WA, WB, wb2, cq, cv, cb, W2c, V2c, bnp);
  pair_attn16<<<8192, 256, 0, stream>>>(S, bo, gamma, beta, bnp, W2c, V2c,
                                        (float*)d_out);
}

// Round 21
// 456.337 us; speedup vs baseline: 1.1539x; 1.0604x over previous
//
#include <hip/hip_runtime.h>
#include <hip/hip_bf16.h>

typedef __attribute__((ext_vector_type(8))) short short8v;
typedef __attribute__((ext_vector_type(4))) float f32x4;
typedef __attribute__((ext_vector_type(8))) unsigned short us8;

#define LDA 264  // 256 + 8 bf16 pad for the S/P tile

__device__ __forceinline__ unsigned short f2bf(float f) {
  union { __hip_bfloat16 h; unsigned short u; } c;
  c.h = __float2bfloat16(f);
  return c.u;
}
__device__ __forceinline__ unsigned int f2bf2(float lo, float hi) {
  union { __hip_bfloat162 h; unsigned int u; } c;
  c.h = __float22bfloat162_rn(make_float2(lo, hi));
  return c.u;
}

// Transpose Wk (256x256 f32) -> WkT so make_w's reads are coalesced.
__global__ __launch_bounds__(256) void tr_wk(const float* __restrict__ Wk,
                                             float* __restrict__ WkT) {
  __shared__ float sT[64][65];
  const int b = blockIdx.x;
  const int bi = b >> 2, bj = b & 3;
  const int tid = threadIdx.x;
  const int r4 = tid >> 6, c64 = tid & 63;
#pragma unroll
  for (int p = 0; p < 16; p++)
    sT[c64][p * 4 + r4] = Wk[(bi * 64 + p * 4 + r4) * 256 + bj * 64 + c64];
  __syncthreads();
#pragma unroll
  for (int p = 0; p < 16; p++)
    WkT[(bj * 64 + p * 4 + r4) * 256 + bi * 64 + c64] = sT[p * 4 + r4][c64];
}

// WA = (Wq@Wk^T)/16, WB = Wv@Wo, wb2 = (Wq@bk)/16, cq = (bq@Wk^T)/16,
// cv = bv@Wo, cb = (bk.bq)/16   (Wk accessed via WkT -> coalesced)
__global__ __launch_bounds__(256) void make_w(
    const float* __restrict__ WkT, const float* __restrict__ Wq,
    const float* __restrict__ Wv, const float* __restrict__ Wo,
    const float* __restrict__ bq, const float* __restrict__ bk,
    const float* __restrict__ bv, float* __restrict__ WA,
    float* __restrict__ WB, float* __restrict__ wb2,
    float* __restrict__ cq, float* __restrict__ cv, float* __restrict__ cb) {
  __shared__ float wq[256], wv[256], bqs[256], bvs[256];
  const int i = blockIdx.x, t = threadIdx.x;
  wq[t] = Wq[i * 256 + t];
  wv[t] = Wv[i * 256 + t];
  bqs[t] = bq[t];
  bvs[t] = bv[t];
  __syncthreads();
  float sa = 0.f, sb = 0.f;
#pragma unroll 8
  for (int d = 0; d < 256; d++) {
    sa = fmaf(wq[d], WkT[d * 256 + t], sa);
    sb = fmaf(wv[d], Wo[d * 256 + t], sb);
  }
  WA[i * 256 + t] = sa * 0.0625f;
  WB[i * 256 + t] = sb;
  if (t == 0) {
    float s = 0.f;
#pragma unroll 8
    for (int d = 0; d < 256; d++) s = fmaf(wq[d], bk[d], s);
    wb2[i] = s * 0.0625f;
  }
  if (i == 0) {
    float s1 = 0.f, s2 = 0.f;
#pragma unroll 8
    for (int d = 0; d < 256; d++) {
      s1 = fmaf(bqs[d], WkT[d * 256 + t], s1);
      s2 = fmaf(bvs[d], Wo[d * 256 + t], s2);
    }
    cq[t] = s1 * 0.0625f;
    cv[t] = s2;
    if (t == 0) {
      float s = 0.f;
      for (int d = 0; d < 256; d++) s = fmaf(bk[d], bqs[d], s);
      cb[0] = s * 0.0625f;
    }
  }
}

// Chunk-major, MFMA-fragment-contiguous B layouts. Wave chunk (4KB) layout:
//   [nt:4][lhi:4][l16:16][j:8]  ->  lane (lhi*16+l16) reads frag nt at
//   byte  nt*1024 + lane*16  (coalesced 1KB global load per fragment).
// W2c: element (n, k):  idx = b*65536 + (k>>5)*8192 + (n>>6)*2048
//                           + ((n>>4)&3)*512 + ((k>>3)&3)*128 + (n&15)*8 + (k&7)
// V2c: element (c, n):  idx = b*65536 + (n>>5)*8192 + (c>>6)*2048
//                           + ((c>>4)&3)*512 + ((n>>3)&3)*128 + (c&15)*8 + (n&7)
// bn[b][n] = hs[n]@wb2 + cb
__global__ __launch_bounds__(256) void prep2(
    const float* __restrict__ hs, const float* __restrict__ WA,
    const float* __restrict__ WB, const float* __restrict__ wb2,
    const float* __restrict__ cq, const float* __restrict__ cv,
    const float* __restrict__ cb, unsigned short* __restrict__ W2c,
    unsigned short* __restrict__ V2c, float* __restrict__ bn) {
  __shared__ float rows[8][256];
  __shared__ float w2s[256];
  const int tid = threadIdx.x;
  const int g0 = blockIdx.x * 8;
#pragma unroll
  for (int j = 0; j < 8; j++) rows[j][tid] = hs[(size_t)(g0 + j) * 256 + tid];
  w2s[tid] = wb2[tid];
  __syncthreads();
  const float cqv = cq[tid], cvv = cv[tid];
  float aq[8], av[8];
#pragma unroll
  for (int j = 0; j < 8; j++) { aq[j] = cqv; av[j] = cvv; }
#pragma unroll 8
  for (int i = 0; i < 256; i++) {
    const float wa = WA[i * 256 + tid];
    const float wb = WB[i * 256 + tid];
#pragma unroll
    for (int j = 0; j < 8; j++) {
      aq[j] = fmaf(rows[j][i], wa, aq[j]);
      av[j] = fmaf(rows[j][i], wb, av[j]);
    }
  }
  const int bb = g0 >> 8, n0 = g0 & 255;
  // W2c: thread holds k=tid for n=n0..n0+7
  {
    const int kc = tid >> 5, lhi = (tid >> 3) & 3, j = tid & 7;
    const int w = n0 >> 6, nt = (n0 >> 4) & 3, l0 = n0 & 15;
    unsigned short* dst = W2c + bb * 65536 + kc * 8192 + w * 2048 + nt * 512 +
                          lhi * 128 + l0 * 8 + j;
#pragma unroll
    for (int jj = 0; jj < 8; jj++) dst[jj * 8] = f2bf(aq[jj]);
  }
  // V2c: thread holds c=tid for n=n0..n0+7 (contiguous j -> us8)
  {
    const int kc = n0 >> 5, lhi = (n0 >> 3) & 3;
    const int w = tid >> 6, nt = (tid >> 4) & 3, l16 = tid & 15;
    us8 vp;
#pragma unroll
    for (int j = 0; j < 8; j++) vp[j] = f2bf(av[j]);
    *(us8*)(V2c + bb * 65536 + kc * 8192 + w * 2048 + nt * 512 + lhi * 128 +
            l16 * 8) = vp;
  }
  if (tid < 8) {
    float s = 0.f;
    for (int i = 0; i < 256; i++) s = fmaf(rows[tid][i], w2s[i], s);
    bn[bb * 256 + n0 + tid] = s + cb[0];
  }
}

// One block: 64 r-rows of one (b,l) pair. B-fragments loaded DIRECTLY from
// global into registers (fragment-contiguous layout => coalesced 1KB loads,
// L2-hot). No B LDS pipe: 36KB LDS -> 4 blocks/CU at (256,4).
__global__ __launch_bounds__(256, 4) void pair_attn16(
    const float* __restrict__ S, const float* __restrict__ bo,
    const float* __restrict__ gamma, const float* __restrict__ beta,
    const float* __restrict__ bn, const unsigned short* __restrict__ W2c,
    const unsigned short* __restrict__ V2c, float* __restrict__ out) {
  __shared__ unsigned short sA[64 * LDA];  // S (bf16), then P (bf16)
  __shared__ float sRed[64 * 8];           // LN partial sums

  const int tid = threadIdx.x;
  const int w = tid >> 6;
  const int lane = tid & 63;
  const int l16 = lane & 15;
  const int lhi = lane >> 4;
  // bijective XCD swizzle: 8192 wgs, 8 XCDs -> each XCD owns one batch
  const int bid = blockIdx.x;
  const int idx = (bid & 7) * 1024 + (bid >> 3);
  const int rblk = idx & 3;
  const int lrow = (idx >> 2) & 255;
  const int bat = idx >> 10;

  const size_t base = ((size_t)((bat * 256 + lrow) * 256 + rblk * 64)) * 256;
  const float* Sblk = S + base;

  // ---- stage S rows -> sA (bf16), 16B LDS writes
#pragma unroll
  for (int it = 0; it < 8; it++) {
    const int c = tid + it * 256;
    const int row = c >> 5, col = (c & 31) << 3;
    const float4 u = *(const float4*)(Sblk + row * 256 + col);
    const float4 v = *(const float4*)(Sblk + row * 256 + col + 4);
    us8 p;
    unsigned int* pu = (unsigned int*)&p;
    pu[0] = f2bf2(u.x, u.y);
    pu[1] = f2bf2(u.z, u.w);
    pu[2] = f2bf2(v.x, v.y);
    pu[3] = f2bf2(v.z, v.w);
    *(us8*)(sA + row * LDA + col) = p;
  }
  float bnv[4];
#pragma unroll
  for (int nt = 0; nt < 4; nt++)
    bnv[nt] = bn[bat * 256 + w * 64 + nt * 16 + l16];
  __syncthreads();  // B1: S staged

  // wave's private column-slice bases (fragment nt at + nt*512 + lane*8)
  const unsigned short* Wb = W2c + (size_t)bat * 65536 + w * 2048;
  const unsigned short* Vb = V2c + (size_t)bat * 65536 + w * 2048;

  f32x4 acc[4][4];
#pragma unroll
  for (int rt = 0; rt < 4; rt++)
#pragma unroll
    for (int nt = 0; nt < 4; nt++) acc[rt][nt] = (f32x4){0.f, 0.f, 0.f, 0.f};

  // ---- GEMM-A: scores = S @ W2; B-frags direct from global (L2-hot)
#pragma unroll
  for (int q = 0; q < 8; q++) {
    short8v a[4], bf[4];
#pragma unroll
    for (int nt = 0; nt < 4; nt++)
      bf[nt] = *(const short8v*)(Wb + q * 8192 + nt * 512 + lane * 8);
#pragma unroll
    for (int rt = 0; rt < 4; rt++)
      a[rt] = *(const short8v*)(sA + (rt * 16 + l16) * LDA + q * 32 + lhi * 8);
#pragma unroll
    for (int rt = 0; rt < 4; rt++)
#pragma unroll
      for (int nt = 0; nt < 4; nt++)
        acc[rt][nt] = __builtin_amdgcn_mfma_f32_16x16x32_bf16(
            a[rt], bf[nt], acc[rt][nt], 0, 0, 0);
  }
  __syncthreads();  // B2: all waves done reading sA (S)

  // ---- exp phase: p = exp(s + bn), unnormalized -> sA (overwrite S)
#pragma unroll
  for (int rt = 0; rt < 4; rt++)
#pragma unroll
    for (int nt = 0; nt < 4; nt++)
#pragma unroll
      for (int rg = 0; rg < 4; rg++)
        sA[(rt * 16 + lhi * 4 + rg) * LDA + (w * 64 + nt * 16 + l16)] =
            f2bf(__expf(acc[rt][nt][rg] + bnv[nt]));
  __syncthreads();  // B3: P visible to all waves

  // ---- GEMM-B: o = P_un @ V2, plus P row-sums via ones-MFMA
  short8v onesv;
#pragma unroll
  for (int j = 0; j < 8; j++) onesv[j] = (short)0x3F80;  // bf16 1.0
  f32x4 ps[4];
#pragma unroll
  for (int rt = 0; rt < 4; rt++) {
    ps[rt] = (f32x4){0.f, 0.f, 0.f, 0.f};
#pragma unroll
    for (int nt = 0; nt < 4; nt++) acc[rt][nt] = (f32x4){0.f, 0.f, 0.f, 0.f};
  }
#pragma unroll
  for (int q = 0; q < 8; q++) {
    short8v a[4], bf[4];
#pragma unroll
    for (int nt = 0; nt < 4; nt++)
      bf[nt] = *(const short8v*)(Vb + q * 8192 + nt * 512 + lane * 8);
#pragma unroll
    for (int rt = 0; rt < 4; rt++)
      a[rt] = *(const short8v*)(sA + (rt * 16 + l16) * LDA + q * 32 + lhi * 8);
#pragma unroll
    for (int rt = 0; rt < 4; rt++) {
#pragma unroll
      for (int nt = 0; nt < 4; nt++)
        acc[rt][nt] = __builtin_amdgcn_mfma_f32_16x16x32_bf16(
            a[rt], bf[nt], acc[rt][nt], 0, 0, 0);
      ps[rt] = __builtin_amdgcn_mfma_f32_16x16x32_bf16(a[rt], onesv, ps[rt],
                                                       0, 0, 0);
    }
  }

  // ---- epilogue: o/rowsum + bo + S residual (f32, L2), LN partial sums
  float bov[4], gv[4], bev[4];
#pragma unroll
  for (int nt = 0; nt < 4; nt++) {
    const int col = w * 64 + nt * 16 + l16;
    bov[nt] = bo[col];
    gv[nt] = gamma[col];
    bev[nt] = beta[col];
  }
#pragma unroll
  for (int rt = 0; rt < 4; rt++)
#pragma unroll
    for (int rg = 0; rg < 4; rg++) {
      const int row = rt * 16 + lhi * 4 + rg;
      const float invr = 1.f / ps[rt][rg];
      const float* Srow = Sblk + row * 256;
      float s1 = 0.f, s2 = 0.f;
#pragma unroll
      for (int nt = 0; nt < 4; nt++) {
        const int col = w * 64 + nt * 16 + l16;
        const float val = acc[rt][nt][rg] * invr + bov[nt] + Srow[col];
        acc[rt][nt][rg] = val;
        s1 += val;
        s2 = fmaf(val, val, s2);
      }
      s1 += __shfl_xor(s1, 1); s2 += __shfl_xor(s2, 1);
      s1 += __shfl_xor(s1, 2); s2 += __shfl_xor(s2, 2);
      s1 += __shfl_xor(s1, 4); s2 += __shfl_xor(s2, 4);
      s1 += __shfl_xor(s1, 8); s2 += __shfl_xor(s2, 8);
      if (l16 == 0) { sRed[row * 8 + w] = s1; sRed[row * 8 + 4 + w] = s2; }
    }
  __syncthreads();  // B4

  float* O = out + base;
#pragma unroll
  for (int rt = 0; rt < 4; rt++)
#pragma unroll
    for (int rg = 0; rg < 4; rg++) {
      const int row = rt * 16 + lhi * 4 + rg;
      f32x4 sa = *(f32x4*)(sRed + row * 8);
      f32x4 sq = *(f32x4*)(sRed + row * 8 + 4);
      const float mean = (sa[0] + sa[1] + sa[2] + sa[3]) * (1.f / 256.f);
      const float ex2 = (sq[0] + sq[1] + sq[2] + sq[3]) * (1.f / 256.f);
      const float rstd = rsqrtf(ex2 - mean * mean + 1e-5f);
      float* Orow = O + row * 256;
#pragma unroll
      for (int nt = 0; nt < 4; nt++) {
        const int col = w * 64 + nt * 16 + l16;
        Orow[col] = (acc[rt][nt][rg] - mean) * rstd * gv[nt] + bev[nt];
      }
    }
}

extern "C" void kernel_launch(void* const* d_in, const int* in_sizes, int n_in,
                              void* d_out, int out_size, void* d_ws, size_t ws_size,
                              hipStream_t stream) {
  const float* hs    = (const float*)d_in[0];
  const float* S     = (const float*)d_in[1];
  const float* Wq    = (const float*)d_in[2];
  const float* bq    = (const float*)d_in[3];
  const float* Wk    = (const float*)d_in[4];
  const float* bk    = (const float*)d_in[5];
  const float* Wv    = (const float*)d_in[6];
  const float* bv    = (const float*)d_in[7];
  const float* Wo    = (const float*)d_in[8];
  const float* bo    = (const float*)d_in[9];
  const float* gamma = (const float*)d_in[10];
  const float* beta  = (const float*)d_in[11];

  unsigned short* W2c = (unsigned short*)d_ws;          // 8*256*256 bf16 = 1MB
  unsigned short* V2c = W2c + 8 * 256 * 256;            // 1MB
  float* WA  = (float*)(V2c + 8 * 256 * 256);           // 256KB
  float* WB  = WA + 256 * 256;                          // 256KB
  float* WkT = WB + 256 * 256;                          // 256KB
  float* wb2 = WkT + 256 * 256;                         // 1KB
  float* cq  = wb2 + 256;
  float* cv  = cq + 256;
  float* cb  = cv + 256;
  float* bnp = cb + 256;                                // 8*256 f32

  tr_wk<<<16, 256, 0, stream>>>(Wk, WkT);
  make_w<<<256, 256, 0, stream>>>(WkT, Wq, Wv, Wo, bq, bk, bv, WA, WB, wb2,
                                  cq, cv, cb);
  prep2<<<256, 256, 0, stream>>>(hs, WA, WB, wb2, cq, cv, cb, W2c, V2c, bnp);
  pair_attn16<<<8192, 256, 0, stream>>>(S, bo, gamma, beta, bnp, W2c, V2c,
                                        (float*)d_out);
}